// Round 12
// baseline (6168.874 us; speedup 1.0000x reference)
//
#include <hip/hip_runtime.h>
#include <hip/hip_bf16.h>

// MDGCRN hybrid: fp32 encoder (argmax-exact path) + bf16-MFMA decoder.
// R12: k_enc un-paired (1 bb/block) -> grid (128,1,8)=1024 blocks = 4
//      blocks/CU (R11 was grid-limited at 2). LDS 34.6 KB. Bit-exact.
//      Decoder = R11 (sup2e + dual-M k_mmB2).

typedef __attribute__((ext_vector_type(8))) short s8v;
typedef __attribute__((ext_vector_type(4))) float f4v;
typedef __attribute__((ext_vector_type(4))) unsigned short u4v;

__device__ __forceinline__ float b2f(unsigned short u){
  union{unsigned int i; float f;} v; v.i = ((unsigned int)u)<<16; return v.f;
}
__device__ __forceinline__ unsigned short f2b(float f){
  union{float f; unsigned int i;} v; v.f = f;
  unsigned int r = v.i + 0x7fff + ((v.i >> 16) & 1);   // RNE (finite inputs only)
  return (unsigned short)(r >> 16);
}

__global__ void k_zero16(uint4* p, int n){
  int i = blockIdx.x*256 + threadIdx.x;
  if (i < n) p[i] = make_uint4(0,0,0,0);
}

// ======================= fp32 ENCODER =======================

__global__ void k_reorderF(const float* __restrict__ W, float* __restrict__ Wr,
                           int HC, int NEX, int SEGW, int J){
  int idx = blockIdx.x*256 + threadIdx.x;
  int K = 3*SEGW;
  if (idx >= K*J) return;
  int k = idx / J, j = idx - k*J;
  int seg = k / SEGW, c = k - seg*SEGW;
  int CIN = HC + NEX;
  float v = 0.f;
  if (c < HC)       v = W[(size_t)(seg*CIN + NEX + c)*J + j];
  else if (c < CIN) v = W[(size_t)(seg*CIN + (c-HC))*J + j];
  Wr[(size_t)k*J + j] = v;
}

// A2e = 2*A@A - I   (512x512)
__global__ __launch_bounds__(256) void k_a2e(const float* __restrict__ A,
                                             float* __restrict__ A2e){
  __shared__ __align__(16) float As[32][132];
  __shared__ __align__(16) float Bs[32][132];
  int t = threadIdx.x;
  int r0 = (blockIdx.x & 3) * 128;
  int c0 = (blockIdx.x >> 2) * 128;
  int tr = t & 15, tc = t >> 4;
  float acc[8][8];
  #pragma unroll
  for (int i=0;i<8;i++)
    #pragma unroll
    for (int j=0;j<8;j++) acc[i][j]=0.f;
  for (int k0=0;k0<512;k0+=32){
    #pragma unroll
    for (int i=0;i<4;i++){
      int s = t + i*256;
      int k = s & 31, rq = s >> 5;
      const float* ap = A + (size_t)(r0 + rq*4)*512 + k0 + k;
      float4 v;
      v.x = ap[0]; v.y = ap[512]; v.z = ap[1024]; v.w = ap[1536];
      *(float4*)&As[k][rq*4] = v;
    }
    #pragma unroll
    for (int i=0;i<4;i++){
      int s = t + i*256;
      int k = s >> 5, cq = s & 31;
      float4 v = *(const float4*)(A + (size_t)(k0+k)*512 + c0 + cq*4);
      *(float4*)&Bs[k][cq*4] = v;
    }
    __syncthreads();
    #pragma unroll 8
    for (int k=0;k<32;k++){
      float a[8], b[8];
      *(float4*)&a[0] = *(const float4*)&As[k][tr*4];
      *(float4*)&a[4] = *(const float4*)&As[k][64+tr*4];
      *(float4*)&b[0] = *(const float4*)&Bs[k][tc*4];
      *(float4*)&b[4] = *(const float4*)&Bs[k][64+tc*4];
      #pragma unroll
      for (int i=0;i<8;i++)
        #pragma unroll
        for (int j=0;j<8;j++) acc[i][j] += a[i]*b[j];
    }
    __syncthreads();
  }
  #pragma unroll
  for (int i=0;i<8;i++){
    int r = r0 + (i<4 ? tr*4+i : 64+tr*4+i-4);
    #pragma unroll
    for (int j=0;j<8;j++){
      int c = c0 + (j<4 ? tc*4+j : 64+tc*4+j-4);
      A2e[(size_t)r*512 + c] = 2.f*acc[i][j] - (r==c ? 1.f : 0.f);
    }
  }
}

// Fused encoder half-step (R12): one bb per block, KC=16 chunks, split G12
// half-buffer. LDS = 17.4 + 17.2 KB = 34.6 KB. Grid dim3(128,1,8)=1024 blocks.
// MODE 0 (gate): sigmoid; j<64 -> zh=s*h, j>=64 -> rbuf=s.
// MODE 1 (upd):  tanh; hnew = r*henc + (1-r)*hc -> henc in-place.
template<int MODE>
__global__ __launch_bounds__(256) void k_enc(
    const float* __restrict__ A, const float* __restrict__ A2e,
    const float* __restrict__ hsrc,             // [row][64] row-major
    const float* __restrict__ xa, const float* __restrict__ xb,  // (64,12,512)
    int tstep, const float* __restrict__ Wr, const float* __restrict__ bias,
    float* __restrict__ zh, float* __restrict__ rbuf, float* __restrict__ henc)
{
  constexpr int J  = (MODE==0) ? 128 : 64;
  constexpr int TN = (MODE==0) ? 8 : 4;
  __shared__ __align__(16) float R1[4352];        // phase1 staging / phase2 G12h
  __shared__ __align__(16) float F0t[65][66];     // G0 own rows, transposed [c][r]
  float (*sA)[68]   = (float(*)[68])(R1);
  float (*sA2)[68]  = (float(*)[68])(R1 + 1088);
  float (*sB)[68]   = (float(*)[68])(R1 + 2176);
  float (*G12h)[66] = (float(*)[66])(R1);         // [65][66] one seg at a time
  const int t = threadIdx.x;
  const int bb = blockIdx.x;                      // 0..127
  const int rowblk = blockIdx.z;
  const int n0 = rowblk * 64;
  const int tr = t & 15, tc = t >> 4;
  const int xrow = t & 63, xmat = (t >> 6) & 1;   // x-col owner iff t<128
  const float* xp = (bb < 64) ? (xa + ((size_t)bb*12 + tstep)*512)
                              : (xb + ((size_t)(bb-64)*12 + tstep)*512);

  float acc[2][4][4];                             // [mat][i][j]
  #pragma unroll
  for (int m=0;m<2;m++)
    #pragma unroll
    for (int i=0;i<4;i++)
      #pragma unroll
      for (int j=0;j<4;j++) acc[m][i][j]=0.f;
  float xacc = 0.f;

  // ---- phase 1: dual conv, KC=16 (k-order identical to R11 -> bit-exact) ----
  for (int k0=0;k0<512;k0+=16){
    {
      int k = t & 15, rq = t >> 4;                // rows rq*4..rq*4+3
      const float* ap  = A   + (size_t)(n0 + rq*4)*512 + k0 + k;
      const float* a2p = A2e + (size_t)(n0 + rq*4)*512 + k0 + k;
      float4 v, w;
      v.x = ap[0];  v.y = ap[512];  v.z = ap[1024];  v.w = ap[1536];
      w.x = a2p[0]; w.y = a2p[512]; w.z = a2p[1024]; w.w = a2p[1536];
      *(float4*)&sA[k][rq*4]  = v;
      *(float4*)&sA2[k][rq*4] = w;
    }
    {
      int k = t >> 4, cq = t & 15;
      *(float4*)&sB[k][cq*4] = *(const float4*)(hsrc + (size_t)(bb*512 + k0 + k)*64 + cq*4);
    }
    if (t < 16) sB[t][64] = xp[k0 + t];
    __syncthreads();
    #pragma unroll 4
    for (int k=0;k<16;k++){
      float a1[4], a2[4], b[4];
      *(float4*)&a1[0] = *(const float4*)&sA[k][tr*4];
      *(float4*)&a2[0] = *(const float4*)&sA2[k][tr*4];
      *(float4*)&b[0]  = *(const float4*)&sB[k][tc*4];
      #pragma unroll
      for (int i=0;i<4;i++)
        #pragma unroll
        for (int j=0;j<4;j++){
          acc[0][i][j] += a1[i]*b[j];
          acc[1][i][j] += a2[i]*b[j];
        }
      float am = xmat ? sA2[k][xrow] : sA[k][xrow];
      xacc += am * sB[k][64];
    }
    // own-rows G0 -> F0t (transposed)
    if ((k0 >> 6) == rowblk){
      const int off = k0 & 63;                    // 0,16,32,48
      for (int s=t; s<1040; s+=256){              // 65 c x 16 k
        int c = s >> 4, kk = s & 15;
        F0t[c][off + kk] = sB[kk][c];
      }
    }
    __syncthreads();
  }

  // ---- phase 2: half-buffered segs; c-order identical to R11 ----
  // G1 (+x G1) into G12h
  #pragma unroll
  for (int j=0;j<4;j++){
    float4 v;
    v.x = acc[0][0][j]; v.y = acc[0][1][j];
    v.z = acc[0][2][j]; v.w = acc[0][3][j];
    *(float4*)&G12h[tc*4 + j][tr*4] = v;
  }
  if (t < 64) G12h[64][xrow] = xacc;              // xmat==0 threads
  __syncthreads();

  float acc2[4][TN];
  #pragma unroll
  for (int i=0;i<4;i++)
    #pragma unroll
    for (int jj=0;jj<TN;jj++) acc2[i][jj]=0.f;
  const int j0 = tc*TN;

  #pragma unroll 4
  for (int c=0;c<65;c++){                         // seg0: W rows 0..64
    float a[4], w[TN];
    *(float4*)&a[0] = *(const float4*)&F0t[c][tr*4];
    #pragma unroll
    for (int q=0;q<TN;q+=4) *(float4*)&w[q] = *(const float4*)(Wr + (size_t)c*J + j0 + q);
    #pragma unroll
    for (int i=0;i<4;i++)
      #pragma unroll
      for (int jj=0;jj<TN;jj++) acc2[i][jj] += a[i]*w[jj];
  }
  #pragma unroll 4
  for (int c=0;c<65;c++){                         // G1 seg: W rows 68..132
    float a[4], w[TN];
    *(float4*)&a[0] = *(const float4*)&G12h[c][tr*4];
    #pragma unroll
    for (int q=0;q<TN;q+=4) *(float4*)&w[q] = *(const float4*)(Wr + (size_t)(68+c)*J + j0 + q);
    #pragma unroll
    for (int i=0;i<4;i++)
      #pragma unroll
      for (int jj=0;jj<TN;jj++) acc2[i][jj] += a[i]*w[jj];
  }
  __syncthreads();
  // G2 (+x G2) into G12h
  #pragma unroll
  for (int j=0;j<4;j++){
    float4 v;
    v.x = acc[1][0][j]; v.y = acc[1][1][j];
    v.z = acc[1][2][j]; v.w = acc[1][3][j];
    *(float4*)&G12h[tc*4 + j][tr*4] = v;
  }
  if (t >= 64 && t < 128) G12h[64][xrow] = xacc;  // xmat==1 threads
  __syncthreads();
  #pragma unroll 4
  for (int c=0;c<65;c++){                         // G2 seg: W rows 136..200
    float a[4], w[TN];
    *(float4*)&a[0] = *(const float4*)&G12h[c][tr*4];
    #pragma unroll
    for (int q=0;q<TN;q+=4) *(float4*)&w[q] = *(const float4*)(Wr + (size_t)(136+c)*J + j0 + q);
    #pragma unroll
    for (int i=0;i<4;i++)
      #pragma unroll
      for (int jj=0;jj<TN;jj++) acc2[i][jj] += a[i]*w[jj];
  }

  float bj[TN];
  #pragma unroll
  for (int jj=0;jj<TN;jj++) bj[jj] = bias[j0+jj];
  const int gbase = bb*512 + n0;
  #pragma unroll
  for (int i=0;i<4;i++){
    const int lr = tr*4 + i;
    const int row = gbase + lr;
    if (MODE == 0){
      float s[8];
      #pragma unroll
      for (int jj=0;jj<TN;jj++) s[jj] = 1.f/(1.f + __expf(-(acc2[i][jj] + bj[jj])));
      if (j0 < 64){
        float4 o0, o1;
        o0.x = s[0]*F0t[j0+0][lr]; o0.y = s[1]*F0t[j0+1][lr];
        o0.z = s[2]*F0t[j0+2][lr]; o0.w = s[3]*F0t[j0+3][lr];
        o1.x = s[4]*F0t[j0+4][lr]; o1.y = s[5]*F0t[j0+5][lr];
        o1.z = s[6]*F0t[j0+6][lr]; o1.w = s[7]*F0t[j0+7][lr];
        *(float4*)(zh + (size_t)row*64 + j0)     = o0;
        *(float4*)(zh + (size_t)row*64 + j0 + 4) = o1;
      } else {
        float4 o0, o1;
        o0.x=s[0]; o0.y=s[1]; o0.z=s[2]; o0.w=s[3];
        o1.x=s[4]; o1.y=s[5]; o1.z=s[6]; o1.w=s[7];
        *(float4*)(rbuf + (size_t)row*64 + j0 - 64) = o0;
        *(float4*)(rbuf + (size_t)row*64 + j0 - 60) = o1;
      }
    } else {
      float4 h4 = *(const float4*)(henc + (size_t)row*64 + j0);
      float4 r4 = *(const float4*)(rbuf + (size_t)row*64 + j0);
      float hv[4] = {h4.x,h4.y,h4.z,h4.w};
      float rv[4] = {r4.x,r4.y,r4.z,r4.w};
      float ov[4];
      #pragma unroll
      for (int jj=0;jj<4;jj++){
        float hc = 1.f - 2.f/(__expf(2.f*(acc2[i][jj] + bj[jj])) + 1.f);
        ov[jj] = rv[jj]*hv[jj] + (1.f - rv[jj])*hc;
      }
      float4 o; o.x=ov[0]; o.y=ov[1]; o.z=ov[2]; o.w=ov[3];
      *(float4*)(henc + (size_t)row*64 + j0) = o;
    }
  }
}

// ======================= bf16 DECODER (R11 verbatim) =======================

__global__ void k_reorderB(const float* __restrict__ W, unsigned short* __restrict__ Wr,
                           int HC, int NEX, int C, int KP, int J){
  int idx = blockIdx.x*256 + threadIdx.x;
  if (idx >= J*KP) return;
  int j = idx / KP, kp = idx - j*KP;
  float v = 0.f;
  if (kp < 3*C){
    int seg = kp / C, c = kp - seg*C;
    int CIN = HC + NEX;
    if (c < HC)       v = W[(size_t)(seg*CIN + NEX + c)*J + j];
    else if (c < CIN) v = W[(size_t)(seg*CIN + (c-HC))*J + j];
  }
  Wr[(size_t)j*KP + kp] = f2b(v);
}

// sup2e = 2*sup@sup - I per bb (bf16, runs once). Grid (4,4,64), 256 thr.
__global__ __launch_bounds__(256) void k_sup2(const unsigned short* __restrict__ S,
                                              unsigned short* __restrict__ S2){
  __shared__ unsigned short Bs[128*40];
  const int t = threadIdx.x;
  const int w = t >> 6, L = t & 63, lm = L & 15, q = L >> 4;
  const int bb = blockIdx.z;
  const int n0 = blockIdx.x * 128;
  const int m0 = blockIdx.y * 128;
  const unsigned short* Sb = S + (size_t)bb * 262144;
  unsigned short* S2b = S2 + (size_t)bb * 262144;
  f4v acc[2][8];
  #pragma unroll
  for (int i=0;i<2;i++)
    #pragma unroll
    for (int j=0;j<8;j++)
      #pragma unroll
      for (int r=0;r<4;r++) acc[i][j][r] = 0.f;
  for (int k0=0;k0<512;k0+=32){
    #pragma unroll
    for (int i=0;i<2;i++){
      int s = t + i*256;
      int kk = s >> 4, mg = s & 15;
      s8v v = *(const s8v*)(Sb + (size_t)(k0+kk)*512 + m0 + mg*8);
      #pragma unroll
      for (int e=0;e<8;e++) Bs[(mg*8+e)*40 + kk] = ((unsigned short*)&v)[e];
    }
    __syncthreads();
    s8v a0 = *(const s8v*)(Sb + (size_t)(n0 + w*32 + lm)*512 + k0 + q*8);
    s8v a1 = *(const s8v*)(Sb + (size_t)(n0 + w*32 + 16 + lm)*512 + k0 + q*8);
    #pragma unroll
    for (int ct=0;ct<8;ct++){
      s8v b = *(const s8v*)&Bs[(ct*16+lm)*40 + q*8];
      acc[0][ct] = __builtin_amdgcn_mfma_f32_16x16x32_bf16(a0, b, acc[0][ct], 0,0,0);
      acc[1][ct] = __builtin_amdgcn_mfma_f32_16x16x32_bf16(a1, b, acc[1][ct], 0,0,0);
    }
    __syncthreads();
  }
  #pragma unroll
  for (int rt=0;rt<2;rt++){
    const int row = n0 + w*32 + rt*16 + q*4;
    #pragma unroll
    for (int ct=0;ct<8;ct++){
      const int col = m0 + ct*16 + lm;
      #pragma unroll
      for (int r=0;r<4;r++){
        float v = 2.f*acc[rt][ct][r] - ((row+r)==col ? 1.f : 0.f);
        S2b[(size_t)(row+r)*512 + col] = f2b(v);
      }
    }
  }
}

// Dual graph conv: G1 = sup@G0 -> seg1, G2 = sup2e@G0 -> seg2. 64-row blocks,
// grid (8,1,64) = 512 blocks (2/CU). Writes fC (col-major) + fR (row-major).
__global__ __launch_bounds__(256) void k_mmB2(
    const unsigned short* __restrict__ M1, const unsigned short* __restrict__ M2,
    unsigned short* fC, unsigned short* fR)
{
  constexpr int C = 144;
  __shared__ unsigned short Bs[C*40];
  const int t = threadIdx.x;
  const int w = t >> 6, L = t & 63, lm = L & 15, q = L >> 4;
  const int bb = blockIdx.z;
  const int n0 = blockIdx.x * 64;
  const unsigned short* M1b = M1 + (size_t)bb * 262144;
  const unsigned short* M2b = M2 + (size_t)bb * 262144;
  unsigned short* fCb = fC + (size_t)bb * 432 * 512;
  const unsigned short* Xb = fCb;                 // seg0 (G0)
  unsigned short* O1 = fCb + (size_t)C * 512;
  unsigned short* O2 = fCb + (size_t)2 * C * 512;
  const int rw = n0 + w*16;

  f4v acc[2][9];
  #pragma unroll
  for (int i=0;i<2;i++)
    #pragma unroll
    for (int j=0;j<9;j++)
      #pragma unroll
      for (int r=0;r<4;r++) acc[i][j][r] = 0.f;

  s8v breg[3];
  const size_t ar = (size_t)(rw + lm)*512 + q*8;
  #pragma unroll
  for (int i=0;i<3;i++){
    int s = t + i*256;
    if (s < C*4) breg[i] = *(const s8v*)(Xb + (size_t)(s>>2)*512 + (s&3)*8);
  }
  s8v a1 = *(const s8v*)(M1b + ar);
  s8v a2 = *(const s8v*)(M2b + ar);

  for (int ks=0; ks<16; ks++){
    #pragma unroll
    for (int i=0;i<3;i++){
      int s = t + i*256;
      if (s < C*4) *(s8v*)&Bs[(s>>2)*40 + (s&3)*8] = breg[i];
    }
    __syncthreads();
    const int kn = (ks < 15) ? (ks+1)*32 : 0;
    #pragma unroll
    for (int i=0;i<3;i++){
      int s = t + i*256;
      if (s < C*4) breg[i] = *(const s8v*)(Xb + (size_t)(s>>2)*512 + kn + (s&3)*8);
    }
    s8v a1n = *(const s8v*)(M1b + ar + kn);
    s8v a2n = *(const s8v*)(M2b + ar + kn);
    #pragma unroll
    for (int ct=0; ct<9; ct++){
      s8v b = *(const s8v*)&Bs[(ct*16+lm)*40 + q*8];
      acc[0][ct] = __builtin_amdgcn_mfma_f32_16x16x32_bf16(a1, b, acc[0][ct], 0,0,0);
      acc[1][ct] = __builtin_amdgcn_mfma_f32_16x16x32_bf16(a2, b, acc[1][ct], 0,0,0);
    }
    __syncthreads();
    a1 = a1n; a2 = a2n;
  }
  const int m0 = rw + q*4;
  #pragma unroll
  for (int ct=0; ct<9; ct++){
    const int c = ct*16 + lm;
    u4v o1, o2;
    #pragma unroll
    for (int r=0;r<4;r++){ o1[r] = f2b(acc[0][ct][r]); o2[r] = f2b(acc[1][ct][r]); }
    *(u4v*)(O1 + (size_t)c*512 + m0) = o1;
    *(u4v*)(O2 + (size_t)c*512 + m0) = o2;
    const size_t rb = (size_t)(bb*512 + m0)*448;
    #pragma unroll
    for (int r=0;r<4;r++){
      fR[rb + (size_t)r*448 + 144 + c] = o1[r];
      fR[rb + (size_t)r*448 + 288 + c] = o2[r];
    }
  }
}

template<int KSTEPS, int JT16, int MODE, int HC>
__global__ __launch_bounds__(256) void k_gwB(
    unsigned short* fR, int KP,
    const unsigned short* __restrict__ Wr, const float* __restrict__ bias,
    unsigned short* fC, int C3,
    float* hC, float* rbuf)
{
  constexpr int JT = JT16*16;
  constexpr int BIT = JT*4/256;
  __shared__ unsigned short Bs[JT*40];
  const int t = threadIdx.x;
  const int w = t >> 6, L = t & 63, lm = L & 15, q = L >> 4;
  const int row0 = blockIdx.x * 128;
  const int j0 = blockIdx.y * JT;
  const int rw = row0 + w*32;

  f4v acc[2][JT16];
  #pragma unroll
  for (int i=0;i<2;i++)
    #pragma unroll
    for (int j=0;j<JT16;j++)
      #pragma unroll
      for (int r=0;r<4;r++) acc[i][j][r] = 0.f;

  s8v breg[BIT];
  const unsigned short* Wb = Wr + (size_t)j0*KP;
  const size_t ar0 = (size_t)(rw + lm)*KP + q*8;
  const size_t ar1 = (size_t)(rw + 16 + lm)*KP + q*8;

  #pragma unroll
  for (int i=0;i<BIT;i++){
    int s = t + i*256;
    breg[i] = *(const s8v*)(Wb + (size_t)(s>>2)*KP + (s&3)*8);
  }
  s8v a0 = *(const s8v*)(fR + ar0);
  s8v a1 = *(const s8v*)(fR + ar1);

  for (int ks=0; ks<KSTEPS; ks++){
    #pragma unroll
    for (int i=0;i<BIT;i++){
      int s = t + i*256;
      *(s8v*)&Bs[(s>>2)*40 + (s&3)*8] = breg[i];
    }
    __syncthreads();
    const int kn = (ks < KSTEPS-1) ? (ks+1)*32 : 0;
    #pragma unroll
    for (int i=0;i<BIT;i++){
      int s = t + i*256;
      breg[i] = *(const s8v*)(Wb + (size_t)(s>>2)*KP + kn + (s&3)*8);
    }
    s8v a0n = *(const s8v*)(fR + ar0 + kn);
    s8v a1n = *(const s8v*)(fR + ar1 + kn);
    #pragma unroll
    for (int ct=0; ct<JT16; ct++){
      s8v b = *(const s8v*)&Bs[(ct*16+lm)*40 + q*8];
      acc[0][ct] = __builtin_amdgcn_mfma_f32_16x16x32_bf16(a0, b, acc[0][ct], 0,0,0);
      acc[1][ct] = __builtin_amdgcn_mfma_f32_16x16x32_bf16(a1, b, acc[1][ct], 0,0,0);
    }
    __syncthreads();
    a0 = a0n; a1 = a1n;
  }
  #pragma unroll
  for (int rt=0; rt<2; rt++){
    const int m0 = rw + rt*16 + q*4;
    const int bb = m0 >> 9, n = m0 & 511;
    #pragma unroll
    for (int ct=0; ct<JT16; ct++){
      const int j = j0 + ct*16 + lm;
      const float bj = bias[j];
      if (MODE == 0){
        if (j < HC){
          f4v h4 = *(const f4v*)(hC + ((size_t)bb*HC + j)*512 + n);
          u4v o;
          #pragma unroll
          for (int r=0;r<4;r++){
            float s = 1.f/(1.f + __expf(-(acc[rt][ct][r] + bj)));
            float zh = s * h4[r];
            o[r] = f2b(zh);
            fR[(size_t)(m0+r)*KP + j] = o[r];
          }
          *(u4v*)(fC + ((size_t)bb*C3 + j)*512 + n) = o;
        } else {
          f4v rv;
          #pragma unroll
          for (int r=0;r<4;r++) rv[r] = 1.f/(1.f + __expf(-(acc[rt][ct][r] + bj)));
          *(f4v*)(rbuf + ((size_t)bb*HC + (j-HC))*512 + n) = rv;
        }
      } else {
        f4v h4 = *(const f4v*)(hC + ((size_t)bb*HC + j)*512 + n);
        f4v r4 = *(const f4v*)(rbuf + ((size_t)bb*HC + j)*512 + n);
        u4v o; f4v hn;
        #pragma unroll
        for (int r=0;r<4;r++){
          float e = __expf(2.f*(acc[rt][ct][r] + bj));
          float hc_ = 1.f - 2.f/(e + 1.f);
          hn[r] = r4[r]*h4[r] + (1.f - r4[r])*hc_;
          o[r] = f2b(hn[r]);
          fR[(size_t)(m0+r)*KP + j] = o[r];
        }
        *(f4v*)(hC + ((size_t)bb*HC + j)*512 + n) = hn;
        *(u4v*)(fC + ((size_t)bb*C3 + j)*512 + n) = o;
      }
    }
  }
}

// ======================= glue kernels =======================

__global__ void k_extras_dec(const float* __restrict__ yc,
    unsigned short* fR, unsigned short* fC, int tstep){
  int rr = blockIdx.x*256 + threadIdx.x;   // 32768
  int bb = rr >> 9, n = rr & 511;
  unsigned short u = f2b(yc[((size_t)bb*12 + tstep)*512 + n]);
  fR[(size_t)rr*448 + 129] = u;
  fC[((size_t)bb*432 + 129)*512 + n] = u;
}
__global__ void k_fix_go(unsigned short* fR, unsigned short* fC){
  int rr = blockIdx.x*256 + threadIdx.x;   // 32768
  int bb = rr >> 9, n = rr & 511;
  fR[(size_t)rr*448 + 128] = 0;
  fC[((size_t)bb*432 + 128)*512 + n] = 0;
}

__global__ __launch_bounds__(256) void k_query(const float* __restrict__ hR,
      const float* __restrict__ Wq, const float* __restrict__ Mem,
      float* __restrict__ hCd, unsigned short* fR, unsigned short* fC,
      int* __restrict__ it, int* __restrict__ ih){
  int sub = threadIdx.x >> 6, lane = threadIdx.x & 63;
  int row = blockIdx.x*4 + sub;          // 0..65535
  __shared__ float sh[4][64], sq[4][64], ss[4][20];
  float hv = hR[(size_t)row*64 + lane];
  sh[sub][lane] = hv;
  __syncthreads();
  float qv = 0.f;
  for (int c=0;c<64;c++) qv += sh[sub][c]*Wq[c*64 + lane];
  sq[sub][lane] = qv;
  __syncthreads();
  if (lane < 20){
    float s = 0.f;
    for (int j=0;j<64;j++) s += sq[sub][j]*Mem[lane*64 + j];
    ss[sub][lane] = s;
  }
  __syncthreads();
  float mx = -1e30f; int am = 0;
  for (int m=0;m<20;m++){ float s = ss[sub][m]; if (s > mx){ mx = s; am = m; } }
  float sum = 0.f;
  for (int m=0;m<20;m++) sum += __expf(ss[sub][m]-mx);
  float inv = 1.f/sum;
  float v = 0.f;
  for (int m=0;m<20;m++) v += __expf(ss[sub][m]-mx)*inv*Mem[m*64 + lane];
  int bb = row >> 9, n = row & 511;
  if (bb < 64){
    hCd[((size_t)bb*128 + lane)*512 + n] = hv;
    hCd[((size_t)bb*128 + 64 + lane)*512 + n] = v;
    fR[(size_t)row*448 + lane] = f2b(hv);
    fR[(size_t)row*448 + 64 + lane] = f2b(v);
    fC[((size_t)bb*432 + lane)*512 + n] = f2b(hv);
    fC[((size_t)bb*432 + 64 + lane)*512 + n] = f2b(v);
    if (lane==0) it[row] = am;
  } else {
    if (lane==0) ih[row - 32768] = am;
  }
}

__global__ void k_latent(const int* __restrict__ it, const int* __restrict__ ih,
                         const float* __restrict__ Mem,
                         const float* __restrict__ lW, const float* __restrict__ lb,
                         float* __restrict__ outl){
  int row = blockIdx.x*256 + threadIdx.x;  // 32768
  int i1 = it[row], i2 = ih[row];
  float a = lb[0];
  for (int c=0;c<64;c++) a += (Mem[i1*64+c]-Mem[i2*64+c])*lW[c];
  outl[row] = 1.f/(1.f + __expf(-a));
}

__global__ __launch_bounds__(256) void k_emb(const float* __restrict__ hCd,
    const float* __restrict__ hW, const float* __restrict__ hb, float* __restrict__ emb){
  __shared__ float sW[1280];
  int t = threadIdx.x;
  for (int s=t; s<1280; s+=256) sW[s] = hW[s];
  __syncthreads();
  int rr = blockIdx.x*256 + t;   // 32768
  int bb = rr >> 9, n = rr & 511;
  float a[10];
  #pragma unroll
  for (int e=0;e<10;e++) a[e] = hb[e];
  for (int c=0;c<128;c++){
    float v = hCd[((size_t)bb*128 + c)*512 + n];
    #pragma unroll
    for (int e=0;e<10;e++) a[e] += v*sW[c*10+e];
  }
  #pragma unroll
  for (int e=0;e<10;e++) emb[(size_t)rr*10 + e] = a[e];
}

__global__ __launch_bounds__(256) void k_support(const float* __restrict__ emb,
                                                 unsigned short* __restrict__ sup){
  int b = blockIdx.x >> 9;
  int n = blockIdx.x & 511;
  int t = threadIdx.x;
  __shared__ float se[5120];
  __shared__ float red[8];
  for (int s = t; s < 5120; s += 256) se[s] = emb[(size_t)b*5120 + s];
  __syncthreads();
  float en[10];
  #pragma unroll
  for (int i=0;i<10;i++) en[i] = se[n*10+i];
  float s0=0.f, s1=0.f;
  #pragma unroll
  for (int i=0;i<10;i++){ s0 += en[i]*se[t*10+i]; s1 += en[i]*se[(t+256)*10+i]; }
  s0 = fmaxf(s0, 0.f); s1 = fmaxf(s1, 0.f);
  float mx = fmaxf(s0, s1);
  for (int o=32;o>0;o>>=1) mx = fmaxf(mx, __shfl_down(mx, o));
  if ((t&63)==0) red[t>>6] = mx;
  __syncthreads();
  mx = fmaxf(fmaxf(red[0],red[1]), fmaxf(red[2],red[3]));
  float e0 = __expf(s0-mx), e1 = __expf(s1-mx);
  float sm = e0 + e1;
  for (int o=32;o>0;o>>=1) sm += __shfl_down(sm, o);
  if ((t&63)==0) red[4+(t>>6)] = sm;
  __syncthreads();
  sm = red[4]+red[5]+red[6]+red[7];
  float inv = 1.f/sm;
  size_t base = ((size_t)b*512 + n)*512;
  sup[base + t]       = f2b(e0*inv);
  sup[base + t + 256] = f2b(e1*inv);
}

__global__ __launch_bounds__(256) void k_proj(const float* __restrict__ hCd,
    const float* __restrict__ pW, const float* __restrict__ pb,
    unsigned short* fR, unsigned short* fC, float* __restrict__ out, int tstep){
  __shared__ float sW[128];
  int t = threadIdx.x;
  if (t < 128) sW[t] = pW[t];
  __syncthreads();
  int rr = blockIdx.x*256 + t;   // 32768
  int bb = rr >> 9, n = rr & 511;
  float a = pb[0];
  for (int c=0;c<128;c++) a += hCd[((size_t)bb*128 + c)*512 + n]*sW[c];
  out[((size_t)bb*12 + tstep)*512 + n] = a;
  unsigned short u = f2b(a);
  fR[(size_t)rr*448 + 128] = u;
  fC[((size_t)bb*432 + 128)*512 + n] = u;
}

extern "C" void kernel_launch(void* const* d_in, const int* in_sizes, int n_in,
                              void* d_out, int out_size, void* d_ws, size_t ws_size,
                              hipStream_t stream) {
  const float* x     = (const float*)d_in[0];
  const float* x_his = (const float*)d_in[2];
  const float* y_cov = (const float*)d_in[3];
  const float* adj   = (const float*)d_in[4];
  const float* egW   = (const float*)d_in[5];
  const float* egb   = (const float*)d_in[6];
  const float* euW   = (const float*)d_in[7];
  const float* eub   = (const float*)d_in[8];
  const float* dgW   = (const float*)d_in[9];
  const float* dgb   = (const float*)d_in[10];
  const float* duW   = (const float*)d_in[11];
  const float* dub   = (const float*)d_in[12];
  const float* Mem   = (const float*)d_in[13];
  const float* Wq    = (const float*)d_in[14];
  const float* hW    = (const float*)d_in[15];
  const float* hb    = (const float*)d_in[16];
  const float* lW    = (const float*)d_in[17];
  const float* lb    = (const float*)d_in[18];
  const float* pW    = (const float*)d_in[19];
  const float* pb    = (const float*)d_in[20];
  float* out  = (float*)d_out;           // (64,12,512,1)
  float* outl = out + 393216;            // (64,512)

  char* base = (char*)d_ws;
  size_t off = 0;
  auto alloc = [&](size_t bytes)->char*{
    char* p = base + off; off = (off + bytes + 255) & ~(size_t)255; return p;
  };
  unsigned short* sup  = (unsigned short*)alloc(33554432);  // 64*512*512 bf16
  unsigned short* sup2 = (unsigned short*)alloc(33554432);  // 2*sup^2 - I
  float* emb  = (float*)alloc(1310720);          // 32768*10
  int*   it   = (int*)alloc(131072);
  int*   ih   = (int*)alloc(131072);
  float* henc = (float*)alloc(16777216);         // (128*512)x64 fp32, row-major
  float* zhF  = (float*)alloc(16777216);         // enc z*h (row-major); hCd alias
  float* hCd  = zhF;                             // (64,128,512) fp32 decoder state
  float* rbF  = (float*)alloc(16777216);         // enc r (row-major) / dec r (col-major)
  unsigned short* fR = (unsigned short*)alloc(29360128);  // 32768 x 448 bf16
  unsigned short* fC = (unsigned short*)alloc(28311552);  // 64 x 432 x 512 bf16
  float* a2e = (float*)alloc(1048576);           // 512x512 fp32
  float* wr_egF = (float*)alloc(104448);         // 204x128 fp32
  float* wr_euF = (float*)alloc(52224);          // 204x64 fp32
  unsigned short* wr_dg = (unsigned short*)alloc(229376); // 256x448 bf16
  unsigned short* wr_du = (unsigned short*)alloc(114688); // 128x448 bf16
  if (ws_size < off) return;

  // init (ws is re-poisoned every call)
  k_zero16<<<4096,256,0,stream>>>((uint4*)henc, 1048576);
  k_zero16<<<7168,256,0,stream>>>((uint4*)fR, 1835008);
  k_zero16<<<6912,256,0,stream>>>((uint4*)fC, 1769472);
  k_a2e<<<16,256,0,stream>>>(adj, a2e);
  k_reorderF<<<102,256,0,stream>>>(egW, wr_egF, 64,1,68,128);
  k_reorderF<<< 51,256,0,stream>>>(euW, wr_euF, 64,1,68,64);
  k_reorderB<<<448,256,0,stream>>>(dgW, wr_dg, 128,2,144,448,256);
  k_reorderB<<<224,256,0,stream>>>(duW, wr_du, 128,2,144,448,128);

  // ---------------- fp32 encoders: fused conv+gw, 1 bb/block ----------------
  for (int t = 0; t < 12; t++){
    k_enc<0><<<dim3(128,1,8),256,0,stream>>>(adj, a2e, henc, x, x_his, t,
                                             wr_egF, egb, zhF, rbF, nullptr);
    k_enc<1><<<dim3(128,1,8),256,0,stream>>>(adj, a2e, zhF, x, x_his, t,
                                             wr_euF, eub, nullptr, rbF, henc);
  }

  // ---------------- memory query / latent / support (fp32 scores) ----------------
  k_query<<<16384,256,0,stream>>>(henc, Wq, Mem, hCd, fR, fC, it, ih);
  k_latent<<<128,256,0,stream>>>(it, ih, Mem, lW, lb, outl);
  k_emb<<<128,256,0,stream>>>(hCd, hW, hb, emb);
  k_support<<<32768,256,0,stream>>>(emb, sup);
  k_sup2<<<dim3(4,4,64),256,0,stream>>>(sup, sup2);
  k_fix_go<<<128,256,0,stream>>>(fR, fC);

  // ---------------- bf16 decoder, BB=64 ----------------
  for (int t = 0; t < 12; t++){
    k_extras_dec<<<128,256,0,stream>>>(y_cov, fR, fC, t);
    k_mmB2<<<dim3(8,1,64),256,0,stream>>>(sup, sup2, fC, fR);
    k_gwB<14,16,0,128><<<dim3(256,1),256,0,stream>>>(fR, 448, wr_dg, dgb, fC, 432, hCd, rbF);
    k_mmB2<<<dim3(8,1,64),256,0,stream>>>(sup, sup2, fC, fR);
    k_gwB<14,8,1,128><<<dim3(256,1),256,0,stream>>>(fR, 448, wr_du, dub, fC, 432, hCd, rbF);
    k_proj<<<128,256,0,stream>>>(hCd, pW, pb, fR, fC, out, t);
  }
}

// Round 13
// 6009.453 us; speedup vs baseline: 1.0265x; 1.0265x over previous
//
#include <hip/hip_runtime.h>
#include <hip/hip_bf16.h>

// MDGCRN hybrid: fp32 encoder (argmax-exact path) + bf16-MFMA decoder.
// R13: (a) k_gwB J-split -> 512 blocks (2/CU, was 1/CU); (b) k_query scatter
//      fix: row-major haugR + LDS-transpose kernel k_tr (coalesced hCd/fC).
//      All math bit-exact vs R12. k_enc = R12.

typedef __attribute__((ext_vector_type(8))) short s8v;
typedef __attribute__((ext_vector_type(4))) float f4v;
typedef __attribute__((ext_vector_type(4))) unsigned short u4v;

__device__ __forceinline__ float b2f(unsigned short u){
  union{unsigned int i; float f;} v; v.i = ((unsigned int)u)<<16; return v.f;
}
__device__ __forceinline__ unsigned short f2b(float f){
  union{float f; unsigned int i;} v; v.f = f;
  unsigned int r = v.i + 0x7fff + ((v.i >> 16) & 1);   // RNE (finite inputs only)
  return (unsigned short)(r >> 16);
}

__global__ void k_zero16(uint4* p, int n){
  int i = blockIdx.x*256 + threadIdx.x;
  if (i < n) p[i] = make_uint4(0,0,0,0);
}

// ======================= fp32 ENCODER =======================

__global__ void k_reorderF(const float* __restrict__ W, float* __restrict__ Wr,
                           int HC, int NEX, int SEGW, int J){
  int idx = blockIdx.x*256 + threadIdx.x;
  int K = 3*SEGW;
  if (idx >= K*J) return;
  int k = idx / J, j = idx - k*J;
  int seg = k / SEGW, c = k - seg*SEGW;
  int CIN = HC + NEX;
  float v = 0.f;
  if (c < HC)       v = W[(size_t)(seg*CIN + NEX + c)*J + j];
  else if (c < CIN) v = W[(size_t)(seg*CIN + (c-HC))*J + j];
  Wr[(size_t)k*J + j] = v;
}

// A2e = 2*A@A - I   (512x512)
__global__ __launch_bounds__(256) void k_a2e(const float* __restrict__ A,
                                             float* __restrict__ A2e){
  __shared__ __align__(16) float As[32][132];
  __shared__ __align__(16) float Bs[32][132];
  int t = threadIdx.x;
  int r0 = (blockIdx.x & 3) * 128;
  int c0 = (blockIdx.x >> 2) * 128;
  int tr = t & 15, tc = t >> 4;
  float acc[8][8];
  #pragma unroll
  for (int i=0;i<8;i++)
    #pragma unroll
    for (int j=0;j<8;j++) acc[i][j]=0.f;
  for (int k0=0;k0<512;k0+=32){
    #pragma unroll
    for (int i=0;i<4;i++){
      int s = t + i*256;
      int k = s & 31, rq = s >> 5;
      const float* ap = A + (size_t)(r0 + rq*4)*512 + k0 + k;
      float4 v;
      v.x = ap[0]; v.y = ap[512]; v.z = ap[1024]; v.w = ap[1536];
      *(float4*)&As[k][rq*4] = v;
    }
    #pragma unroll
    for (int i=0;i<4;i++){
      int s = t + i*256;
      int k = s >> 5, cq = s & 31;
      float4 v = *(const float4*)(A + (size_t)(k0+k)*512 + c0 + cq*4);
      *(float4*)&Bs[k][cq*4] = v;
    }
    __syncthreads();
    #pragma unroll 8
    for (int k=0;k<32;k++){
      float a[8], b[8];
      *(float4*)&a[0] = *(const float4*)&As[k][tr*4];
      *(float4*)&a[4] = *(const float4*)&As[k][64+tr*4];
      *(float4*)&b[0] = *(const float4*)&Bs[k][tc*4];
      *(float4*)&b[4] = *(const float4*)&Bs[k][64+tc*4];
      #pragma unroll
      for (int i=0;i<8;i++)
        #pragma unroll
        for (int j=0;j<8;j++) acc[i][j] += a[i]*b[j];
    }
    __syncthreads();
  }
  #pragma unroll
  for (int i=0;i<8;i++){
    int r = r0 + (i<4 ? tr*4+i : 64+tr*4+i-4);
    #pragma unroll
    for (int j=0;j<8;j++){
      int c = c0 + (j<4 ? tc*4+j : 64+tc*4+j-4);
      A2e[(size_t)r*512 + c] = 2.f*acc[i][j] - (r==c ? 1.f : 0.f);
    }
  }
}

// Fused encoder half-step (R12): one bb per block, KC=16 chunks, split G12
// half-buffer. LDS 34.6 KB. Grid dim3(128,1,8).
template<int MODE>
__global__ __launch_bounds__(256) void k_enc(
    const float* __restrict__ A, const float* __restrict__ A2e,
    const float* __restrict__ hsrc,             // [row][64] row-major
    const float* __restrict__ xa, const float* __restrict__ xb,  // (64,12,512)
    int tstep, const float* __restrict__ Wr, const float* __restrict__ bias,
    float* __restrict__ zh, float* __restrict__ rbuf, float* __restrict__ henc)
{
  constexpr int J  = (MODE==0) ? 128 : 64;
  constexpr int TN = (MODE==0) ? 8 : 4;
  __shared__ __align__(16) float R1[4352];        // phase1 staging / phase2 G12h
  __shared__ __align__(16) float F0t[65][66];     // G0 own rows, transposed [c][r]
  float (*sA)[68]   = (float(*)[68])(R1);
  float (*sA2)[68]  = (float(*)[68])(R1 + 1088);
  float (*sB)[68]   = (float(*)[68])(R1 + 2176);
  float (*G12h)[66] = (float(*)[66])(R1);         // [65][66] one seg at a time
  const int t = threadIdx.x;
  const int bb = blockIdx.x;                      // 0..127
  const int rowblk = blockIdx.z;
  const int n0 = rowblk * 64;
  const int tr = t & 15, tc = t >> 4;
  const int xrow = t & 63, xmat = (t >> 6) & 1;
  const float* xp = (bb < 64) ? (xa + ((size_t)bb*12 + tstep)*512)
                              : (xb + ((size_t)(bb-64)*12 + tstep)*512);

  float acc[2][4][4];                             // [mat][i][j]
  #pragma unroll
  for (int m=0;m<2;m++)
    #pragma unroll
    for (int i=0;i<4;i++)
      #pragma unroll
      for (int j=0;j<4;j++) acc[m][i][j]=0.f;
  float xacc = 0.f;

  // ---- phase 1: dual conv, KC=16 ----
  for (int k0=0;k0<512;k0+=16){
    {
      int k = t & 15, rq = t >> 4;
      const float* ap  = A   + (size_t)(n0 + rq*4)*512 + k0 + k;
      const float* a2p = A2e + (size_t)(n0 + rq*4)*512 + k0 + k;
      float4 v, w;
      v.x = ap[0];  v.y = ap[512];  v.z = ap[1024];  v.w = ap[1536];
      w.x = a2p[0]; w.y = a2p[512]; w.z = a2p[1024]; w.w = a2p[1536];
      *(float4*)&sA[k][rq*4]  = v;
      *(float4*)&sA2[k][rq*4] = w;
    }
    {
      int k = t >> 4, cq = t & 15;
      *(float4*)&sB[k][cq*4] = *(const float4*)(hsrc + (size_t)(bb*512 + k0 + k)*64 + cq*4);
    }
    if (t < 16) sB[t][64] = xp[k0 + t];
    __syncthreads();
    #pragma unroll 4
    for (int k=0;k<16;k++){
      float a1[4], a2[4], b[4];
      *(float4*)&a1[0] = *(const float4*)&sA[k][tr*4];
      *(float4*)&a2[0] = *(const float4*)&sA2[k][tr*4];
      *(float4*)&b[0]  = *(const float4*)&sB[k][tc*4];
      #pragma unroll
      for (int i=0;i<4;i++)
        #pragma unroll
        for (int j=0;j<4;j++){
          acc[0][i][j] += a1[i]*b[j];
          acc[1][i][j] += a2[i]*b[j];
        }
      float am = xmat ? sA2[k][xrow] : sA[k][xrow];
      xacc += am * sB[k][64];
    }
    if ((k0 >> 6) == rowblk){
      const int off = k0 & 63;
      for (int s=t; s<1040; s+=256){
        int c = s >> 4, kk = s & 15;
        F0t[c][off + kk] = sB[kk][c];
      }
    }
    __syncthreads();
  }

  // ---- phase 2: half-buffered segs ----
  #pragma unroll
  for (int j=0;j<4;j++){
    float4 v;
    v.x = acc[0][0][j]; v.y = acc[0][1][j];
    v.z = acc[0][2][j]; v.w = acc[0][3][j];
    *(float4*)&G12h[tc*4 + j][tr*4] = v;
  }
  if (t < 64) G12h[64][xrow] = xacc;
  __syncthreads();

  float acc2[4][TN];
  #pragma unroll
  for (int i=0;i<4;i++)
    #pragma unroll
    for (int jj=0;jj<TN;jj++) acc2[i][jj]=0.f;
  const int j0 = tc*TN;

  #pragma unroll 4
  for (int c=0;c<65;c++){
    float a[4], w[TN];
    *(float4*)&a[0] = *(const float4*)&F0t[c][tr*4];
    #pragma unroll
    for (int q=0;q<TN;q+=4) *(float4*)&w[q] = *(const float4*)(Wr + (size_t)c*J + j0 + q);
    #pragma unroll
    for (int i=0;i<4;i++)
      #pragma unroll
      for (int jj=0;jj<TN;jj++) acc2[i][jj] += a[i]*w[jj];
  }
  #pragma unroll 4
  for (int c=0;c<65;c++){
    float a[4], w[TN];
    *(float4*)&a[0] = *(const float4*)&G12h[c][tr*4];
    #pragma unroll
    for (int q=0;q<TN;q+=4) *(float4*)&w[q] = *(const float4*)(Wr + (size_t)(68+c)*J + j0 + q);
    #pragma unroll
    for (int i=0;i<4;i++)
      #pragma unroll
      for (int jj=0;jj<TN;jj++) acc2[i][jj] += a[i]*w[jj];
  }
  __syncthreads();
  #pragma unroll
  for (int j=0;j<4;j++){
    float4 v;
    v.x = acc[1][0][j]; v.y = acc[1][1][j];
    v.z = acc[1][2][j]; v.w = acc[1][3][j];
    *(float4*)&G12h[tc*4 + j][tr*4] = v;
  }
  if (t >= 64 && t < 128) G12h[64][xrow] = xacc;
  __syncthreads();
  #pragma unroll 4
  for (int c=0;c<65;c++){
    float a[4], w[TN];
    *(float4*)&a[0] = *(const float4*)&G12h[c][tr*4];
    #pragma unroll
    for (int q=0;q<TN;q+=4) *(float4*)&w[q] = *(const float4*)(Wr + (size_t)(136+c)*J + j0 + q);
    #pragma unroll
    for (int i=0;i<4;i++)
      #pragma unroll
      for (int jj=0;jj<TN;jj++) acc2[i][jj] += a[i]*w[jj];
  }

  float bj[TN];
  #pragma unroll
  for (int jj=0;jj<TN;jj++) bj[jj] = bias[j0+jj];
  const int gbase = bb*512 + n0;
  #pragma unroll
  for (int i=0;i<4;i++){
    const int lr = tr*4 + i;
    const int row = gbase + lr;
    if (MODE == 0){
      float s[8];
      #pragma unroll
      for (int jj=0;jj<TN;jj++) s[jj] = 1.f/(1.f + __expf(-(acc2[i][jj] + bj[jj])));
      if (j0 < 64){
        float4 o0, o1;
        o0.x = s[0]*F0t[j0+0][lr]; o0.y = s[1]*F0t[j0+1][lr];
        o0.z = s[2]*F0t[j0+2][lr]; o0.w = s[3]*F0t[j0+3][lr];
        o1.x = s[4]*F0t[j0+4][lr]; o1.y = s[5]*F0t[j0+5][lr];
        o1.z = s[6]*F0t[j0+6][lr]; o1.w = s[7]*F0t[j0+7][lr];
        *(float4*)(zh + (size_t)row*64 + j0)     = o0;
        *(float4*)(zh + (size_t)row*64 + j0 + 4) = o1;
      } else {
        float4 o0, o1;
        o0.x=s[0]; o0.y=s[1]; o0.z=s[2]; o0.w=s[3];
        o1.x=s[4]; o1.y=s[5]; o1.z=s[6]; o1.w=s[7];
        *(float4*)(rbuf + (size_t)row*64 + j0 - 64) = o0;
        *(float4*)(rbuf + (size_t)row*64 + j0 - 60) = o1;
      }
    } else {
      float4 h4 = *(const float4*)(henc + (size_t)row*64 + j0);
      float4 r4 = *(const float4*)(rbuf + (size_t)row*64 + j0);
      float hv[4] = {h4.x,h4.y,h4.z,h4.w};
      float rv[4] = {r4.x,r4.y,r4.z,r4.w};
      float ov[4];
      #pragma unroll
      for (int jj=0;jj<4;jj++){
        float hc = 1.f - 2.f/(__expf(2.f*(acc2[i][jj] + bj[jj])) + 1.f);
        ov[jj] = rv[jj]*hv[jj] + (1.f - rv[jj])*hc;
      }
      float4 o; o.x=ov[0]; o.y=ov[1]; o.z=ov[2]; o.w=ov[3];
      *(float4*)(henc + (size_t)row*64 + j0) = o;
    }
  }
}

// ======================= bf16 DECODER =======================

__global__ void k_reorderB(const float* __restrict__ W, unsigned short* __restrict__ Wr,
                           int HC, int NEX, int C, int KP, int J){
  int idx = blockIdx.x*256 + threadIdx.x;
  if (idx >= J*KP) return;
  int j = idx / KP, kp = idx - j*KP;
  float v = 0.f;
  if (kp < 3*C){
    int seg = kp / C, c = kp - seg*C;
    int CIN = HC + NEX;
    if (c < HC)       v = W[(size_t)(seg*CIN + NEX + c)*J + j];
    else if (c < CIN) v = W[(size_t)(seg*CIN + (c-HC))*J + j];
  }
  Wr[(size_t)j*KP + kp] = f2b(v);
}

// sup2e = 2*sup@sup - I per bb (bf16, once). Grid (4,4,64), 256 thr.
__global__ __launch_bounds__(256) void k_sup2(const unsigned short* __restrict__ S,
                                              unsigned short* __restrict__ S2){
  __shared__ unsigned short Bs[128*40];
  const int t = threadIdx.x;
  const int w = t >> 6, L = t & 63, lm = L & 15, q = L >> 4;
  const int bb = blockIdx.z;
  const int n0 = blockIdx.x * 128;
  const int m0 = blockIdx.y * 128;
  const unsigned short* Sb = S + (size_t)bb * 262144;
  unsigned short* S2b = S2 + (size_t)bb * 262144;
  f4v acc[2][8];
  #pragma unroll
  for (int i=0;i<2;i++)
    #pragma unroll
    for (int j=0;j<8;j++)
      #pragma unroll
      for (int r=0;r<4;r++) acc[i][j][r] = 0.f;
  for (int k0=0;k0<512;k0+=32){
    #pragma unroll
    for (int i=0;i<2;i++){
      int s = t + i*256;
      int kk = s >> 4, mg = s & 15;
      s8v v = *(const s8v*)(Sb + (size_t)(k0+kk)*512 + m0 + mg*8);
      #pragma unroll
      for (int e=0;e<8;e++) Bs[(mg*8+e)*40 + kk] = ((unsigned short*)&v)[e];
    }
    __syncthreads();
    s8v a0 = *(const s8v*)(Sb + (size_t)(n0 + w*32 + lm)*512 + k0 + q*8);
    s8v a1 = *(const s8v*)(Sb + (size_t)(n0 + w*32 + 16 + lm)*512 + k0 + q*8);
    #pragma unroll
    for (int ct=0;ct<8;ct++){
      s8v b = *(const s8v*)&Bs[(ct*16+lm)*40 + q*8];
      acc[0][ct] = __builtin_amdgcn_mfma_f32_16x16x32_bf16(a0, b, acc[0][ct], 0,0,0);
      acc[1][ct] = __builtin_amdgcn_mfma_f32_16x16x32_bf16(a1, b, acc[1][ct], 0,0,0);
    }
    __syncthreads();
  }
  #pragma unroll
  for (int rt=0;rt<2;rt++){
    const int row = n0 + w*32 + rt*16 + q*4;
    #pragma unroll
    for (int ct=0;ct<8;ct++){
      const int col = m0 + ct*16 + lm;
      #pragma unroll
      for (int r=0;r<4;r++){
        float v = 2.f*acc[rt][ct][r] - ((row+r)==col ? 1.f : 0.f);
        S2b[(size_t)(row+r)*512 + col] = f2b(v);
      }
    }
  }
}

// Dual graph conv: G1 = sup@G0, G2 = sup2e@G0. Grid (8,1,64).
__global__ __launch_bounds__(256) void k_mmB2(
    const unsigned short* __restrict__ M1, const unsigned short* __restrict__ M2,
    unsigned short* fC, unsigned short* fR)
{
  constexpr int C = 144;
  __shared__ unsigned short Bs[C*40];
  const int t = threadIdx.x;
  const int w = t >> 6, L = t & 63, lm = L & 15, q = L >> 4;
  const int bb = blockIdx.z;
  const int n0 = blockIdx.x * 64;
  const unsigned short* M1b = M1 + (size_t)bb * 262144;
  const unsigned short* M2b = M2 + (size_t)bb * 262144;
  unsigned short* fCb = fC + (size_t)bb * 432 * 512;
  const unsigned short* Xb = fCb;
  unsigned short* O1 = fCb + (size_t)C * 512;
  unsigned short* O2 = fCb + (size_t)2 * C * 512;
  const int rw = n0 + w*16;

  f4v acc[2][9];
  #pragma unroll
  for (int i=0;i<2;i++)
    #pragma unroll
    for (int j=0;j<9;j++)
      #pragma unroll
      for (int r=0;r<4;r++) acc[i][j][r] = 0.f;

  s8v breg[3];
  const size_t ar = (size_t)(rw + lm)*512 + q*8;
  #pragma unroll
  for (int i=0;i<3;i++){
    int s = t + i*256;
    if (s < C*4) breg[i] = *(const s8v*)(Xb + (size_t)(s>>2)*512 + (s&3)*8);
  }
  s8v a1 = *(const s8v*)(M1b + ar);
  s8v a2 = *(const s8v*)(M2b + ar);

  for (int ks=0; ks<16; ks++){
    #pragma unroll
    for (int i=0;i<3;i++){
      int s = t + i*256;
      if (s < C*4) *(s8v*)&Bs[(s>>2)*40 + (s&3)*8] = breg[i];
    }
    __syncthreads();
    const int kn = (ks < 15) ? (ks+1)*32 : 0;
    #pragma unroll
    for (int i=0;i<3;i++){
      int s = t + i*256;
      if (s < C*4) breg[i] = *(const s8v*)(Xb + (size_t)(s>>2)*512 + kn + (s&3)*8);
    }
    s8v a1n = *(const s8v*)(M1b + ar + kn);
    s8v a2n = *(const s8v*)(M2b + ar + kn);
    #pragma unroll
    for (int ct=0; ct<9; ct++){
      s8v b = *(const s8v*)&Bs[(ct*16+lm)*40 + q*8];
      acc[0][ct] = __builtin_amdgcn_mfma_f32_16x16x32_bf16(a1, b, acc[0][ct], 0,0,0);
      acc[1][ct] = __builtin_amdgcn_mfma_f32_16x16x32_bf16(a2, b, acc[1][ct], 0,0,0);
    }
    __syncthreads();
    a1 = a1n; a2 = a2n;
  }
  const int m0 = rw + q*4;
  #pragma unroll
  for (int ct=0; ct<9; ct++){
    const int c = ct*16 + lm;
    u4v o1, o2;
    #pragma unroll
    for (int r=0;r<4;r++){ o1[r] = f2b(acc[0][ct][r]); o2[r] = f2b(acc[1][ct][r]); }
    *(u4v*)(O1 + (size_t)c*512 + m0) = o1;
    *(u4v*)(O2 + (size_t)c*512 + m0) = o2;
    const size_t rb = (size_t)(bb*512 + m0)*448;
    #pragma unroll
    for (int r=0;r<4;r++){
      fR[rb + (size_t)r*448 + 144 + c] = o1[r];
      fR[rb + (size_t)r*448 + 288 + c] = o2[r];
    }
  }
}

template<int KSTEPS, int JT16, int MODE, int HC>
__global__ __launch_bounds__(256) void k_gwB(
    unsigned short* fR, int KP,
    const unsigned short* __restrict__ Wr, const float* __restrict__ bias,
    unsigned short* fC, int C3,
    float* hC, float* rbuf)
{
  constexpr int JT = JT16*16;
  constexpr int BIT = JT*4/256;
  __shared__ unsigned short Bs[JT*40];
  const int t = threadIdx.x;
  const int w = t >> 6, L = t & 63, lm = L & 15, q = L >> 4;
  const int row0 = blockIdx.x * 128;
  const int j0 = blockIdx.y * JT;
  const int rw = row0 + w*32;

  f4v acc[2][JT16];
  #pragma unroll
  for (int i=0;i<2;i++)
    #pragma unroll
    for (int j=0;j<JT16;j++)
      #pragma unroll
      for (int r=0;r<4;r++) acc[i][j][r] = 0.f;

  s8v breg[BIT];
  const unsigned short* Wb = Wr + (size_t)j0*KP;
  const size_t ar0 = (size_t)(rw + lm)*KP + q*8;
  const size_t ar1 = (size_t)(rw + 16 + lm)*KP + q*8;

  #pragma unroll
  for (int i=0;i<BIT;i++){
    int s = t + i*256;
    breg[i] = *(const s8v*)(Wb + (size_t)(s>>2)*KP + (s&3)*8);
  }
  s8v a0 = *(const s8v*)(fR + ar0);
  s8v a1 = *(const s8v*)(fR + ar1);

  for (int ks=0; ks<KSTEPS; ks++){
    #pragma unroll
    for (int i=0;i<BIT;i++){
      int s = t + i*256;
      *(s8v*)&Bs[(s>>2)*40 + (s&3)*8] = breg[i];
    }
    __syncthreads();
    const int kn = (ks < KSTEPS-1) ? (ks+1)*32 : 0;
    #pragma unroll
    for (int i=0;i<BIT;i++){
      int s = t + i*256;
      breg[i] = *(const s8v*)(Wb + (size_t)(s>>2)*KP + kn + (s&3)*8);
    }
    s8v a0n = *(const s8v*)(fR + ar0 + kn);
    s8v a1n = *(const s8v*)(fR + ar1 + kn);
    #pragma unroll
    for (int ct=0; ct<JT16; ct++){
      s8v b = *(const s8v*)&Bs[(ct*16+lm)*40 + q*8];
      acc[0][ct] = __builtin_amdgcn_mfma_f32_16x16x32_bf16(a0, b, acc[0][ct], 0,0,0);
      acc[1][ct] = __builtin_amdgcn_mfma_f32_16x16x32_bf16(a1, b, acc[1][ct], 0,0,0);
    }
    __syncthreads();
    a0 = a0n; a1 = a1n;
  }
  #pragma unroll
  for (int rt=0; rt<2; rt++){
    const int m0 = rw + rt*16 + q*4;
    const int bb = m0 >> 9, n = m0 & 511;
    #pragma unroll
    for (int ct=0; ct<JT16; ct++){
      const int j = j0 + ct*16 + lm;
      const float bj = bias[j];
      if (MODE == 0){
        if (j < HC){
          f4v h4 = *(const f4v*)(hC + ((size_t)bb*HC + j)*512 + n);
          u4v o;
          #pragma unroll
          for (int r=0;r<4;r++){
            float s = 1.f/(1.f + __expf(-(acc[rt][ct][r] + bj)));
            float zh = s * h4[r];
            o[r] = f2b(zh);
            fR[(size_t)(m0+r)*KP + j] = o[r];
          }
          *(u4v*)(fC + ((size_t)bb*C3 + j)*512 + n) = o;
        } else {
          f4v rv;
          #pragma unroll
          for (int r=0;r<4;r++) rv[r] = 1.f/(1.f + __expf(-(acc[rt][ct][r] + bj)));
          *(f4v*)(rbuf + ((size_t)bb*HC + (j-HC))*512 + n) = rv;
        }
      } else {
        f4v h4 = *(const f4v*)(hC + ((size_t)bb*HC + j)*512 + n);
        f4v r4 = *(const f4v*)(rbuf + ((size_t)bb*HC + j)*512 + n);
        u4v o; f4v hn;
        #pragma unroll
        for (int r=0;r<4;r++){
          float e = __expf(2.f*(acc[rt][ct][r] + bj));
          float hc_ = 1.f - 2.f/(e + 1.f);
          hn[r] = r4[r]*h4[r] + (1.f - r4[r])*hc_;
          o[r] = f2b(hn[r]);
          fR[(size_t)(m0+r)*KP + j] = o[r];
        }
        *(f4v*)(hC + ((size_t)bb*HC + j)*512 + n) = hn;
        *(u4v*)(fC + ((size_t)bb*C3 + j)*512 + n) = o;
      }
    }
  }
}

// ======================= glue kernels =======================

__global__ void k_extras_dec(const float* __restrict__ yc,
    unsigned short* fR, unsigned short* fC, int tstep){
  int rr = blockIdx.x*256 + threadIdx.x;   // 32768
  int bb = rr >> 9, n = rr & 511;
  unsigned short u = f2b(yc[((size_t)bb*12 + tstep)*512 + n]);
  fR[(size_t)rr*448 + 129] = u;
  fC[((size_t)bb*432 + 129)*512 + n] = u;
}
__global__ void k_fix_go(unsigned short* fR, unsigned short* fC){
  int rr = blockIdx.x*256 + threadIdx.x;   // 32768
  int bb = rr >> 9, n = rr & 511;
  fR[(size_t)rr*448 + 128] = 0;
  fC[((size_t)bb*432 + 128)*512 + n] = 0;
}

// query: scores/argmax/value; writes haugR row-major (coalesced) + fR + it/ih
__global__ __launch_bounds__(256) void k_query(const float* __restrict__ hR,
      const float* __restrict__ Wq, const float* __restrict__ Mem,
      float* __restrict__ haugR, unsigned short* fR,
      int* __restrict__ it, int* __restrict__ ih){
  int sub = threadIdx.x >> 6, lane = threadIdx.x & 63;
  int row = blockIdx.x*4 + sub;          // 0..65535
  __shared__ float sh[4][64], sq[4][64], ss[4][20];
  float hv = hR[(size_t)row*64 + lane];
  sh[sub][lane] = hv;
  __syncthreads();
  float qv = 0.f;
  for (int c=0;c<64;c++) qv += sh[sub][c]*Wq[c*64 + lane];
  sq[sub][lane] = qv;
  __syncthreads();
  if (lane < 20){
    float s = 0.f;
    for (int j=0;j<64;j++) s += sq[sub][j]*Mem[lane*64 + j];
    ss[sub][lane] = s;
  }
  __syncthreads();
  float mx = -1e30f; int am = 0;
  for (int m=0;m<20;m++){ float s = ss[sub][m]; if (s > mx){ mx = s; am = m; } }
  float sum = 0.f;
  for (int m=0;m<20;m++) sum += __expf(ss[sub][m]-mx);
  float inv = 1.f/sum;
  float v = 0.f;
  for (int m=0;m<20;m++) v += __expf(ss[sub][m]-mx)*inv*Mem[m*64 + lane];
  int bb = row >> 9;
  if (bb < 64){
    haugR[(size_t)row*128 + lane]      = hv;
    haugR[(size_t)row*128 + 64 + lane] = v;
    fR[(size_t)row*448 + lane]      = f2b(hv);
    fR[(size_t)row*448 + 64 + lane] = f2b(v);
    if (lane==0) it[row] = am;
  } else {
    if (lane==0) ih[row - 32768] = am;
  }
}

// transpose haugR [bb*512+n][c] -> hCd fp32 col-major + fC bf16 col-major
// grid (8 n-tiles, 2 c-tiles, 64 bb), 256 thr, 64x64 tiles.
__global__ __launch_bounds__(256) void k_tr(const float* __restrict__ haugR,
      float* __restrict__ hCd, unsigned short* fC){
  __shared__ float T[64][65];
  const int t = threadIdx.x;
  const int n0 = blockIdx.x * 64;
  const int c0 = blockIdx.y * 64;
  const int bb = blockIdx.z;
  #pragma unroll
  for (int i=0;i<16;i++){
    int idx = t + i*256;
    int nl = idx >> 6, cl = idx & 63;
    T[cl][nl] = haugR[(size_t)(bb*512 + n0 + nl)*128 + c0 + cl];
  }
  __syncthreads();
  #pragma unroll
  for (int i=0;i<16;i++){
    int idx = t + i*256;
    int cl = idx >> 6, nl = idx & 63;
    float v = T[cl][nl];
    hCd[((size_t)bb*128 + c0 + cl)*512 + n0 + nl] = v;
    fC[((size_t)bb*432 + c0 + cl)*512 + n0 + nl] = f2b(v);
  }
}

__global__ void k_latent(const int* __restrict__ it, const int* __restrict__ ih,
                         const float* __restrict__ Mem,
                         const float* __restrict__ lW, const float* __restrict__ lb,
                         float* __restrict__ outl){
  int row = blockIdx.x*256 + threadIdx.x;  // 32768
  int i1 = it[row], i2 = ih[row];
  float a = lb[0];
  for (int c=0;c<64;c++) a += (Mem[i1*64+c]-Mem[i2*64+c])*lW[c];
  outl[row] = 1.f/(1.f + __expf(-a));
}

__global__ __launch_bounds__(256) void k_emb(const float* __restrict__ hCd,
    const float* __restrict__ hW, const float* __restrict__ hb, float* __restrict__ emb){
  __shared__ float sW[1280];
  int t = threadIdx.x;
  for (int s=t; s<1280; s+=256) sW[s] = hW[s];
  __syncthreads();
  int rr = blockIdx.x*256 + t;   // 32768
  int bb = rr >> 9, n = rr & 511;
  float a[10];
  #pragma unroll
  for (int e=0;e<10;e++) a[e] = hb[e];
  for (int c=0;c<128;c++){
    float v = hCd[((size_t)bb*128 + c)*512 + n];
    #pragma unroll
    for (int e=0;e<10;e++) a[e] += v*sW[c*10+e];
  }
  #pragma unroll
  for (int e=0;e<10;e++) emb[(size_t)rr*10 + e] = a[e];
}

__global__ __launch_bounds__(256) void k_support(const float* __restrict__ emb,
                                                 unsigned short* __restrict__ sup){
  int b = blockIdx.x >> 9;
  int n = blockIdx.x & 511;
  int t = threadIdx.x;
  __shared__ float se[5120];
  __shared__ float red[8];
  for (int s = t; s < 5120; s += 256) se[s] = emb[(size_t)b*5120 + s];
  __syncthreads();
  float en[10];
  #pragma unroll
  for (int i=0;i<10;i++) en[i] = se[n*10+i];
  float s0=0.f, s1=0.f;
  #pragma unroll
  for (int i=0;i<10;i++){ s0 += en[i]*se[t*10+i]; s1 += en[i]*se[(t+256)*10+i]; }
  s0 = fmaxf(s0, 0.f); s1 = fmaxf(s1, 0.f);
  float mx = fmaxf(s0, s1);
  for (int o=32;o>0;o>>=1) mx = fmaxf(mx, __shfl_down(mx, o));
  if ((t&63)==0) red[t>>6] = mx;
  __syncthreads();
  mx = fmaxf(fmaxf(red[0],red[1]), fmaxf(red[2],red[3]));
  float e0 = __expf(s0-mx), e1 = __expf(s1-mx);
  float sm = e0 + e1;
  for (int o=32;o>0;o>>=1) sm += __shfl_down(sm, o);
  if ((t&63)==0) red[4+(t>>6)] = sm;
  __syncthreads();
  sm = red[4]+red[5]+red[6]+red[7];
  float inv = 1.f/sm;
  size_t base = ((size_t)b*512 + n)*512;
  sup[base + t]       = f2b(e0*inv);
  sup[base + t + 256] = f2b(e1*inv);
}

__global__ __launch_bounds__(256) void k_proj(const float* __restrict__ hCd,
    const float* __restrict__ pW, const float* __restrict__ pb,
    unsigned short* fR, unsigned short* fC, float* __restrict__ out, int tstep){
  __shared__ float sW[128];
  int t = threadIdx.x;
  if (t < 128) sW[t] = pW[t];
  __syncthreads();
  int rr = blockIdx.x*256 + t;   // 32768
  int bb = rr >> 9, n = rr & 511;
  float a = pb[0];
  for (int c=0;c<128;c++) a += hCd[((size_t)bb*128 + c)*512 + n]*sW[c];
  out[((size_t)bb*12 + tstep)*512 + n] = a;
  unsigned short u = f2b(a);
  fR[(size_t)rr*448 + 128] = u;
  fC[((size_t)bb*432 + 128)*512 + n] = u;
}

extern "C" void kernel_launch(void* const* d_in, const int* in_sizes, int n_in,
                              void* d_out, int out_size, void* d_ws, size_t ws_size,
                              hipStream_t stream) {
  const float* x     = (const float*)d_in[0];
  const float* x_his = (const float*)d_in[2];
  const float* y_cov = (const float*)d_in[3];
  const float* adj   = (const float*)d_in[4];
  const float* egW   = (const float*)d_in[5];
  const float* egb   = (const float*)d_in[6];
  const float* euW   = (const float*)d_in[7];
  const float* eub   = (const float*)d_in[8];
  const float* dgW   = (const float*)d_in[9];
  const float* dgb   = (const float*)d_in[10];
  const float* duW   = (const float*)d_in[11];
  const float* dub   = (const float*)d_in[12];
  const float* Mem   = (const float*)d_in[13];
  const float* Wq    = (const float*)d_in[14];
  const float* hW    = (const float*)d_in[15];
  const float* hb    = (const float*)d_in[16];
  const float* lW    = (const float*)d_in[17];
  const float* lb    = (const float*)d_in[18];
  const float* pW    = (const float*)d_in[19];
  const float* pb    = (const float*)d_in[20];
  float* out  = (float*)d_out;           // (64,12,512,1)
  float* outl = out + 393216;            // (64,512)

  char* base = (char*)d_ws;
  size_t off = 0;
  auto alloc = [&](size_t bytes)->char*{
    char* p = base + off; off = (off + bytes + 255) & ~(size_t)255; return p;
  };
  unsigned short* sup  = (unsigned short*)alloc(33554432);  // 64*512*512 bf16
  unsigned short* sup2 = (unsigned short*)alloc(33554432);  // 2*sup^2 - I
  float* emb  = (float*)alloc(1310720);          // 32768*10
  int*   it   = (int*)alloc(131072);
  int*   ih   = (int*)alloc(131072);
  float* henc = (float*)alloc(16777216);         // (128*512)x64 fp32, row-major
  float* zhF  = (float*)alloc(16777216);         // enc z*h (row-major); hCd alias
  float* hCd  = zhF;                             // (64,128,512) fp32 decoder state
  float* rbF  = (float*)alloc(16777216);         // enc r / dec r ; haugR alias
  float* haugR = rbF;                            // (64*512)x128 fp32 (query phase)
  unsigned short* fR = (unsigned short*)alloc(29360128);  // 32768 x 448 bf16
  unsigned short* fC = (unsigned short*)alloc(28311552);  // 64 x 432 x 512 bf16
  float* a2e = (float*)alloc(1048576);           // 512x512 fp32
  float* wr_egF = (float*)alloc(104448);         // 204x128 fp32
  float* wr_euF = (float*)alloc(52224);          // 204x64 fp32
  unsigned short* wr_dg = (unsigned short*)alloc(229376); // 256x448 bf16
  unsigned short* wr_du = (unsigned short*)alloc(114688); // 128x448 bf16
  if (ws_size < off) return;

  // init (ws is re-poisoned every call)
  k_zero16<<<4096,256,0,stream>>>((uint4*)henc, 1048576);
  k_zero16<<<7168,256,0,stream>>>((uint4*)fR, 1835008);
  k_zero16<<<6912,256,0,stream>>>((uint4*)fC, 1769472);
  k_a2e<<<16,256,0,stream>>>(adj, a2e);
  k_reorderF<<<102,256,0,stream>>>(egW, wr_egF, 64,1,68,128);
  k_reorderF<<< 51,256,0,stream>>>(euW, wr_euF, 64,1,68,64);
  k_reorderB<<<448,256,0,stream>>>(dgW, wr_dg, 128,2,144,448,256);
  k_reorderB<<<224,256,0,stream>>>(duW, wr_du, 128,2,144,448,128);

  // ---------------- fp32 encoders: fused conv+gw, 1 bb/block ----------------
  for (int t = 0; t < 12; t++){
    k_enc<0><<<dim3(128,1,8),256,0,stream>>>(adj, a2e, henc, x, x_his, t,
                                             wr_egF, egb, zhF, rbF, nullptr);
    k_enc<1><<<dim3(128,1,8),256,0,stream>>>(adj, a2e, zhF, x, x_his, t,
                                             wr_euF, eub, nullptr, rbF, henc);
  }

  // ---------------- memory query / latent / support (fp32 scores) ----------------
  k_query<<<16384,256,0,stream>>>(henc, Wq, Mem, haugR, fR, it, ih);
  k_tr<<<dim3(8,2,64),256,0,stream>>>(haugR, hCd, fC);
  k_latent<<<128,256,0,stream>>>(it, ih, Mem, lW, lb, outl);
  k_emb<<<128,256,0,stream>>>(hCd, hW, hb, emb);
  k_support<<<32768,256,0,stream>>>(emb, sup);
  k_sup2<<<dim3(4,4,64),256,0,stream>>>(sup, sup2);
  k_fix_go<<<128,256,0,stream>>>(fR, fC);

  // ---------------- bf16 decoder, BB=64 ----------------
  for (int t = 0; t < 12; t++){
    k_extras_dec<<<128,256,0,stream>>>(y_cov, fR, fC, t);
    k_mmB2<<<dim3(8,1,64),256,0,stream>>>(sup, sup2, fC, fR);
    k_gwB<14,8,0,128><<<dim3(256,2),256,0,stream>>>(fR, 448, wr_dg, dgb, fC, 432, hCd, rbF);
    k_mmB2<<<dim3(8,1,64),256,0,stream>>>(sup, sup2, fC, fR);
    k_gwB<14,4,1,128><<<dim3(256,2),256,0,stream>>>(fR, 448, wr_du, dub, fC, 432, hCd, rbF);
    k_proj<<<128,256,0,stream>>>(hCd, pW, pb, fR, fC, out, t);
  }
}